// Round 9
// baseline (162.578 us; speedup 1.0000x reference)
//
#include <hip/hip_runtime.h>

// SparseDopplerAttention on gfx950 — R11: DIAGNOSTIC build (intentional 2x work).
// R7's kernel (~32 us) is invisible in rocprof: the harness's 268 MB poison
// fills (~43 us x5) own the top-5, so R8/R9/R10 flew without counters and all
// three theory levers (occupancy, LDS latency/packing, LDS bytes/CU) came back
// neutral. R11 wraps the EXACT R7 body in a rep x2 loop (same rows, same
// values rewritten; deterministic) so the dispatch runs ~64 us and surfaces
// VALUBusy / MfmaUtil / OccupancyPercent / LDS_BANK_CONFLICT for the true
// kernel shape (grid 256, 1 block/CU, 16 waves, 93 KB LDS).
// Decision rule (committed before seeing data):
//   VALUBusy >= 50%            -> trans/VALU throughput-bound: poly-exp next
//   all pipes < 30%            -> latency-bound: setprio / chain restructure
//   LDS_BANK_CONFLICT >> 1e6   -> swizzle defect: fix layout
// Math identical to R7: out[q] = (sum_k P*vsum)/(sum_k P), LDS-staged bf16
// weights, swizzled Kb, no-max log2-domain softmax.

#define SCALE 0.18033688011112042f   // log2(e)/8

typedef __bf16 bf16;
typedef bf16 v4bf __attribute__((ext_vector_type(4)));
typedef bf16 v8bf __attribute__((ext_vector_type(8)));
typedef float v4f __attribute__((ext_vector_type(4)));

__device__ __forceinline__ v8bf pk8(float4 a, float4 b) {
    v8bf r;
    r[0] = (bf16)a.x; r[1] = (bf16)a.y; r[2] = (bf16)a.z; r[3] = (bf16)a.w;
    r[4] = (bf16)b.x; r[5] = (bf16)b.y; r[6] = (bf16)b.z; r[7] = (bf16)b.w;
    return r;
}
__device__ __forceinline__ float d4(float4 a, v4f w) {
    return a.x * w[0] + a.y * w[1] + a.z * w[2] + a.w * w[3];
}

__global__ __launch_bounds__(1024, 4)
void sda_kernel(const float* __restrict__ power,
                const int*   __restrict__ ele_i,
                const int*   __restrict__ azi_i,
                const float* __restrict__ ele_t,
                const float* __restrict__ azi_t,
                const float* __restrict__ Wq, const float* __restrict__ bq,
                const float* __restrict__ Wk, const float* __restrict__ bk,
                const float* __restrict__ Wv, const float* __restrict__ bv,
                float* __restrict__ out)
{
    extern __shared__ char smem[];
    char*  Kb   = smem;                      // 64 KB: K [key][dim] bf16, 128 B rows, blk16 ^= key&7
    float* vsum = (float*)(smem + 65536);    // 512 f32
    float* wvs  = (float*)(smem + 67584);    // 96 col-sums of Wv + [96]=sum(bv)
    bf16*  WqL  = (bf16*)(smem + 68096);     // 12 KB: Wq bf16 row-major [64][96]
    bf16*  WkL  = (bf16*)(smem + 80384);     // 12 KB: Wk bf16 row-major [64][96]
    float* bqL  = (float*)(smem + 92672);    // 64 f32
    float* bkL  = (float*)(smem + 92928);    // 64 f32
    float* pbuf = (float*)smem;              // prologue-only: 832 f32 inside Kb

    const int tid  = threadIdx.x;
    const int wave = tid >> 6;
    const int lane = tid & 63;
    const int l15  = lane & 15;
    const int quad = lane >> 4;
    const int rowbase = blockIdx.x * 512 + wave * 32;   // this wave's 32 rows

#pragma unroll 1
    for (int rep = 0; rep < 2; ++rep) {
        // rep boundary: previous rep's Phase B reads of Kb must finish before
        // pbuf (aliased into Kb) is rewritten below.
        __syncthreads();

        // ---- issue cold loads: indices -> power rows -> table gathers ----
        int IE[2], IA[2];
#pragma unroll
        for (int mt = 0; mt < 2; mt++) {
            int row = rowbase + mt * 16 + l15;
            IE[mt] = ele_i[row];
            IA[mt] = azi_i[row];
        }
        float4 A[2][4];
#pragma unroll
        for (int mt = 0; mt < 2; mt++) {
            const float* pr = power + (size_t)(rowbase + mt * 16 + l15) * 64;
            A[mt][0] = *(const float4*)(pr + quad * 8);
            A[mt][1] = *(const float4*)(pr + quad * 8 + 4);
            A[mt][2] = *(const float4*)(pr + 32 + quad * 8);
            A[mt][3] = *(const float4*)(pr + 32 + quad * 8 + 4);
        }
        float4 T0[2], T1[2];
#pragma unroll
        for (int mt = 0; mt < 2; mt++) {
            const float* tb = (quad < 2) ? (ele_t + IE[mt] * 16 + quad * 8)
                                         : (azi_t + IA[mt] * 16 + (quad - 2) * 8);
            T0[mt] = *(const float4*)tb;
            T1[mt] = *(const float4*)(tb + 4);
        }

        // ---- prologue: weights -> bf16 LDS; Wv col-sum partials; bv; biases ----
#pragma unroll
        for (int i = 0; i < 6; i++) {
            int idx = tid + i * 1024;            // 6144 elements each
            WqL[idx] = (bf16)Wq[idx];
            WkL[idx] = (bf16)Wk[idx];
        }
        if (tid < 768) {
            int c = tid % 96;
            int g = tid / 96;                    // 0..7, rows g*8..g*8+7
            float s = 0.f;
#pragma unroll
            for (int r = 0; r < 8; r++) s += Wv[(g * 8 + r) * 96 + c];
            pbuf[g * 96 + c] = s;
        } else if (tid < 832) {
            pbuf[768 + (tid - 768)] = bv[tid - 768];
        }
        if (tid < 64) { bqL[tid] = bq[tid]; bkL[tid] = bk[tid]; }
        __syncthreads();                         // BAR1: staging + partials done
        if (tid < 96) {
            float s = 0.f;
#pragma unroll
            for (int g = 0; g < 8; g++) s += pbuf[g * 96 + tid];
            wvs[tid] = s;
        } else if (tid == 96) {
            float s = 0.f;
#pragma unroll
            for (int j = 0; j < 64; j++) s += pbuf[768 + j];
            wvs[96] = s;
        }
        __syncthreads();                         // BAR2: wvs ready (pbuf dead)

        // ---- x fragments (from regs) + fp32 vsum ----
        v4f w0 = *(const v4f*)(wvs + quad * 8);
        v4f w1 = *(const v4f*)(wvs + quad * 8 + 4);
        v4f w2 = *(const v4f*)(wvs + 32 + quad * 8);
        v4f w3 = *(const v4f*)(wvs + 32 + quad * 8 + 4);
        v4f w4 = *(const v4f*)(wvs + 64 + quad * 8);
        v4f w5 = *(const v4f*)(wvs + 64 + quad * 8 + 4);
        const float bvs = wvs[96];

        v8bf xa[2][3];
#pragma unroll
        for (int mt = 0; mt < 2; mt++) {
            xa[mt][0] = pk8(A[mt][0], A[mt][1]);
            xa[mt][1] = pk8(A[mt][2], A[mt][3]);
            xa[mt][2] = pk8(T0[mt], T1[mt]);
            float d = d4(A[mt][0], w0) + d4(A[mt][1], w1) + d4(A[mt][2], w2)
                    + d4(A[mt][3], w3) + d4(T0[mt], w4) + d4(T1[mt], w5);
            d += __shfl_xor(d, 16);
            d += __shfl_xor(d, 32);
            if (quad == 0) vsum[wave * 32 + mt * 16 + l15] = d + bvs;
        }

        // ---- Q^T = Wq @ x^T (weights from LDS), fold SCALE, transpose via own K region ----
        char* Sw = Kb + wave * 4096;   // this wave's 32 K-rows; used first as Q scratch
#pragma unroll 1
        for (int mtd = 0; mtd < 4; mtd++) {
            const bf16* wrow = WqL + (mtd * 16 + l15) * 96;
            v8bf wq3[3];
#pragma unroll
            for (int kt = 0; kt < 3; kt++)
                wq3[kt] = *(const v8bf*)(wrow + kt * 32 + quad * 8);
            float4 bq4 = *(const float4*)(bqL + mtd * 16 + quad * 4);
#pragma unroll
            for (int ntr = 0; ntr < 2; ntr++) {
                v4f acc = {0.f, 0.f, 0.f, 0.f};
#pragma unroll
                for (int kt = 0; kt < 3; kt++)
                    acc = __builtin_amdgcn_mfma_f32_16x16x32_bf16(wq3[kt], xa[ntr][kt], acc, 0, 0, 0);
                int row = ntr * 16 + l15;   // local query
                v4bf o;
                o[0] = (bf16)((acc[0] + bq4.x) * SCALE);
                o[1] = (bf16)((acc[1] + bq4.y) * SCALE);
                o[2] = (bf16)((acc[2] + bq4.z) * SCALE);
                o[3] = (bf16)((acc[3] + bq4.w) * SCALE);
                *(v4bf*)(Sw + row * 128 +
                         ((((mtd * 2 + (quad >> 1)) ^ (row & 7)) << 4) | ((quad & 1) << 3))) = o;
            }
        }
        v8bf qf[2][2];
#pragma unroll
        for (int nt = 0; nt < 2; nt++)
#pragma unroll
            for (int kt = 0; kt < 2; kt++)
                qf[nt][kt] = *(const v8bf*)(Sw + (nt * 16 + l15) * 128 +
                                            (((kt * 4 + quad) ^ (l15 & 7)) << 4));

        // ---- K^T = Wk @ x^T (weights from LDS), write over the scratch ----
#pragma unroll 1
        for (int mtd = 0; mtd < 4; mtd++) {
            const bf16* wrow = WkL + (mtd * 16 + l15) * 96;
            v8bf wk3[3];
#pragma unroll
            for (int kt = 0; kt < 3; kt++)
                wk3[kt] = *(const v8bf*)(wrow + kt * 32 + quad * 8);
            float4 bk4 = *(const float4*)(bkL + mtd * 16 + quad * 4);
#pragma unroll
            for (int ntr = 0; ntr < 2; ntr++) {
                v4f acc = {0.f, 0.f, 0.f, 0.f};
#pragma unroll
                for (int kt = 0; kt < 3; kt++)
                    acc = __builtin_amdgcn_mfma_f32_16x16x32_bf16(wk3[kt], xa[ntr][kt], acc, 0, 0, 0);
                int keyb = wave * 32 + ntr * 16 + l15;
                v4bf o;
                o[0] = (bf16)(acc[0] + bk4.x);
                o[1] = (bf16)(acc[1] + bk4.y);
                o[2] = (bf16)(acc[2] + bk4.z);
                o[3] = (bf16)(acc[3] + bk4.w);
                *(v4bf*)(Kb + keyb * 128 +
                         ((((mtd * 2 + (quad >> 1)) ^ (keyb & 7)) << 4) | ((quad & 1) << 3))) = o;
            }
        }
        __syncthreads();                         // BAR3: K tile + vsum complete

        // ---- Phase B: S^T = K @ Q^T, exp2, weighted accumulate with vsum ----
        float osum[2] = {0.f, 0.f};
        float lsum[2] = {0.f, 0.f};
#pragma unroll 2
        for (int t = 0; t < 16; t++) {
            v8bf kf[2][2];
#pragma unroll
            for (int mtk = 0; mtk < 2; mtk++)
#pragma unroll
                for (int kt = 0; kt < 2; kt++) {
                    int key = t * 32 + mtk * 16 + l15;
                    kf[mtk][kt] = *(const v8bf*)(Kb + key * 128 + (((kt * 4 + quad) ^ (key & 7)) << 4));
                }
            v4f vs[2];
#pragma unroll
            for (int mtk = 0; mtk < 2; mtk++)
                vs[mtk] = *(const v4f*)(vsum + t * 32 + mtk * 16 + quad * 4);
#pragma unroll
            for (int mtk = 0; mtk < 2; mtk++) {
#pragma unroll
                for (int nt = 0; nt < 2; nt++) {
                    v4f acc = {0.f, 0.f, 0.f, 0.f};
                    acc = __builtin_amdgcn_mfma_f32_16x16x32_bf16(kf[mtk][0], qf[nt][0], acc, 0, 0, 0);
                    acc = __builtin_amdgcn_mfma_f32_16x16x32_bf16(kf[mtk][1], qf[nt][1], acc, 0, 0, 0);
                    float p0 = __builtin_amdgcn_exp2f(acc[0]);
                    float p1 = __builtin_amdgcn_exp2f(acc[1]);
                    float p2 = __builtin_amdgcn_exp2f(acc[2]);
                    float p3 = __builtin_amdgcn_exp2f(acc[3]);
                    lsum[nt] += (p0 + p1) + (p2 + p3);
                    osum[nt] += ((p0 * vs[mtk][0] + p1 * vs[mtk][1]) +
                                 (p2 * vs[mtk][2] + p3 * vs[mtk][3]));
                }
            }
        }

        // ---- epilogue: reduce over key-quads, out = osum/lsum ----
#pragma unroll
        for (int nt = 0; nt < 2; nt++) {
            float lv = lsum[nt];
            lv += __shfl_xor(lv, 16);
            lv += __shfl_xor(lv, 32);
            float ov = osum[nt];
            ov += __shfl_xor(ov, 16);
            ov += __shfl_xor(ov, 32);
            if (quad == 0) out[rowbase + nt * 16 + l15] = ov / lv;
        }
    }
}

extern "C" void kernel_launch(void* const* d_in, const int* in_sizes, int n_in,
                              void* d_out, int out_size, void* d_ws, size_t ws_size,
                              hipStream_t stream) {
    const float* power = (const float*)d_in[0];
    const int*   ele_i = (const int*)d_in[1];
    // d_in[2] = range_indices: unused by the reference (positional reshape)
    const int*   azi_i = (const int*)d_in[3];
    const float* ele_t = (const float*)d_in[4];
    const float* azi_t = (const float*)d_in[5];
    const float* Wq = (const float*)d_in[6];
    const float* bq = (const float*)d_in[7];
    const float* Wk = (const float*)d_in[8];
    const float* bk = (const float*)d_in[9];
    const float* Wv = (const float*)d_in[10];
    const float* bv = (const float*)d_in[11];
    float* out = (float*)d_out;

    // Kb 64K + vsum 2K + wvs 512B + WqL 12K + WkL 12K + bqL 256B + bkL 256B
    const int lds_bytes = 93184;
    (void)hipFuncSetAttribute(reinterpret_cast<const void*>(sda_kernel),
                              hipFuncAttributeMaxDynamicSharedMemorySize, lds_bytes);
    sda_kernel<<<256, 1024, lds_bytes, stream>>>(power, ele_i, azi_i, ele_t, azi_t,
                                                 Wq, bq, Wk, bk, Wv, bv, out);
}

// Round 10
// 109.294 us; speedup vs baseline: 1.4875x; 1.4875x over previous
//
#include <hip/hip_runtime.h>

// SparseDopplerAttention on gfx950 — R13 (base = R7; one variable: register
// discipline to kill scratch spills).
// R11 diagnostic (2x-rep R7 body, counters visible): MfmaUtil 11%, VALUBusy 26%,
// Occ 38% -> latency/stall-bound; and WRITE_SIZE 61 MB vs 0.5 MB output =
// ~30 MB/rep SCRATCH SPILL at VGPR_Count=64. Root cause: R7's "pre-issue cold
// loads" held A[2][4]+T0/T1+IE/IA (~44 VGPR) across the whole prologue on top
// of xa(24)+weight frags. R13 reverts to inline loads in the mt loop with
// incremental vsum dot (a0..a5 never co-live) and reads wvs slices from LDS at
// use (no 24-reg w0..w5). Everything else identical to R7: LDS-staged bf16
// Wq/Wk, swizzled Kb, no-max log2-domain softmax, grid 256x1024, 93 KB LDS.
// Identity: out[q] = (sum_k P[q,k]*vsum[k]) / (sum_k P[q,k]),
//   vsum[k] = x[k] . colsum(Wv) + sum(bv) (fp32) — V/PV GEMMs eliminated.

#define SCALE 0.18033688011112042f   // log2(e)/8

typedef __bf16 bf16;
typedef bf16 v4bf __attribute__((ext_vector_type(4)));
typedef bf16 v8bf __attribute__((ext_vector_type(8)));
typedef float v4f __attribute__((ext_vector_type(4)));

__device__ __forceinline__ v8bf pk8(float4 a, float4 b) {
    v8bf r;
    r[0] = (bf16)a.x; r[1] = (bf16)a.y; r[2] = (bf16)a.z; r[3] = (bf16)a.w;
    r[4] = (bf16)b.x; r[5] = (bf16)b.y; r[6] = (bf16)b.z; r[7] = (bf16)b.w;
    return r;
}
__device__ __forceinline__ float d4(float4 a, v4f w) {
    return a.x * w[0] + a.y * w[1] + a.z * w[2] + a.w * w[3];
}

__global__ __launch_bounds__(1024, 4)
void sda_kernel(const float* __restrict__ power,
                const int*   __restrict__ ele_i,
                const int*   __restrict__ azi_i,
                const float* __restrict__ ele_t,
                const float* __restrict__ azi_t,
                const float* __restrict__ Wq, const float* __restrict__ bq,
                const float* __restrict__ Wk, const float* __restrict__ bk,
                const float* __restrict__ Wv, const float* __restrict__ bv,
                float* __restrict__ out)
{
    extern __shared__ char smem[];
    char*  Kb   = smem;                      // 64 KB: K [key][dim] bf16, 128 B rows, blk16 ^= key&7
    float* vsum = (float*)(smem + 65536);    // 512 f32
    float* wvs  = (float*)(smem + 67584);    // 96 col-sums of Wv + [96]=sum(bv)
    bf16*  WqL  = (bf16*)(smem + 68096);     // 12 KB: Wq bf16 row-major [64][96]
    bf16*  WkL  = (bf16*)(smem + 80384);     // 12 KB: Wk bf16 row-major [64][96]
    float* bqL  = (float*)(smem + 92672);    // 64 f32
    float* bkL  = (float*)(smem + 92928);    // 64 f32
    float* pbuf = (float*)smem;              // prologue-only: 832 f32 inside Kb

    const int tid  = threadIdx.x;
    const int wave = tid >> 6;
    const int lane = tid & 63;
    const int l15  = lane & 15;
    const int quad = lane >> 4;
    const int rowbase = blockIdx.x * 512 + wave * 32;   // this wave's 32 rows

    // ---- prologue: weights -> bf16 LDS; Wv col-sum partials; bv; biases ----
#pragma unroll
    for (int i = 0; i < 6; i++) {
        int idx = tid + i * 1024;            // 6144 elements each
        WqL[idx] = (bf16)Wq[idx];
        WkL[idx] = (bf16)Wk[idx];
    }
    if (tid < 768) {
        int c = tid % 96;
        int g = tid / 96;                    // 0..7, rows g*8..g*8+7
        float s = 0.f;
#pragma unroll
        for (int r = 0; r < 8; r++) s += Wv[(g * 8 + r) * 96 + c];
        pbuf[g * 96 + c] = s;
    } else if (tid < 832) {
        pbuf[768 + (tid - 768)] = bv[tid - 768];
    }
    if (tid < 64) { bqL[tid] = bq[tid]; bkL[tid] = bk[tid]; }
    __syncthreads();                         // BAR1: staging + partials done
    if (tid < 96) {
        float s = 0.f;
#pragma unroll
        for (int g = 0; g < 8; g++) s += pbuf[g * 96 + tid];
        wvs[tid] = s;
    } else if (tid == 96) {
        float s = 0.f;
#pragma unroll
        for (int j = 0; j < 64; j++) s += pbuf[768 + j];
        wvs[96] = s;
    }
    __syncthreads();                         // BAR2: wvs ready (pbuf dead)

    // ---- x fragments (inline loads, incremental vsum dot; low pressure) ----
    v8bf xa[2][3];
#pragma unroll
    for (int mt = 0; mt < 2; mt++) {
        int row = rowbase + mt * 16 + l15;
        const float* pr = power + (size_t)row * 64;
        float d;
        {
            float4 a0 = *(const float4*)(pr + quad * 8);
            float4 a1 = *(const float4*)(pr + quad * 8 + 4);
            xa[mt][0] = pk8(a0, a1);
            d  = d4(a0, *(const v4f*)(wvs + quad * 8))
               + d4(a1, *(const v4f*)(wvs + quad * 8 + 4));
        }
        {
            float4 a2 = *(const float4*)(pr + 32 + quad * 8);
            float4 a3 = *(const float4*)(pr + 32 + quad * 8 + 4);
            xa[mt][1] = pk8(a2, a3);
            d += d4(a2, *(const v4f*)(wvs + 32 + quad * 8))
               + d4(a3, *(const v4f*)(wvs + 32 + quad * 8 + 4));
        }
        {
            int ie = ele_i[row];
            int ia = azi_i[row];
            const float* tb = (quad < 2) ? (ele_t + ie * 16 + quad * 8)
                                         : (azi_t + ia * 16 + (quad - 2) * 8);
            float4 a4 = *(const float4*)tb;
            float4 a5 = *(const float4*)(tb + 4);
            xa[mt][2] = pk8(a4, a5);
            d += d4(a4, *(const v4f*)(wvs + 64 + quad * 8))
               + d4(a5, *(const v4f*)(wvs + 64 + quad * 8 + 4));
        }
        d += __shfl_xor(d, 16);
        d += __shfl_xor(d, 32);
        if (quad == 0) vsum[wave * 32 + mt * 16 + l15] = d + wvs[96];
    }

    // ---- Q^T = Wq @ x^T (weights from LDS), fold SCALE, transpose via own K region ----
    char* Sw = Kb + wave * 4096;   // this wave's 32 K-rows; used first as Q scratch
#pragma unroll 1
    for (int mtd = 0; mtd < 4; mtd++) {
        const bf16* wrow = WqL + (mtd * 16 + l15) * 96;
        v8bf wq3[3];
#pragma unroll
        for (int kt = 0; kt < 3; kt++)
            wq3[kt] = *(const v8bf*)(wrow + kt * 32 + quad * 8);
        float4 bq4 = *(const float4*)(bqL + mtd * 16 + quad * 4);
#pragma unroll
        for (int ntr = 0; ntr < 2; ntr++) {
            v4f acc = {0.f, 0.f, 0.f, 0.f};
#pragma unroll
            for (int kt = 0; kt < 3; kt++)
                acc = __builtin_amdgcn_mfma_f32_16x16x32_bf16(wq3[kt], xa[ntr][kt], acc, 0, 0, 0);
            int row = ntr * 16 + l15;   // local query
            v4bf o;
            o[0] = (bf16)((acc[0] + bq4.x) * SCALE);
            o[1] = (bf16)((acc[1] + bq4.y) * SCALE);
            o[2] = (bf16)((acc[2] + bq4.z) * SCALE);
            o[3] = (bf16)((acc[3] + bq4.w) * SCALE);
            *(v4bf*)(Sw + row * 128 +
                     ((((mtd * 2 + (quad >> 1)) ^ (row & 7)) << 4) | ((quad & 1) << 3))) = o;
        }
    }
    v8bf qf[2][2];
#pragma unroll
    for (int nt = 0; nt < 2; nt++)
#pragma unroll
        for (int kt = 0; kt < 2; kt++)
            qf[nt][kt] = *(const v8bf*)(Sw + (nt * 16 + l15) * 128 +
                                        (((kt * 4 + quad) ^ (l15 & 7)) << 4));

    // ---- K^T = Wk @ x^T (weights from LDS), write over the scratch ----
#pragma unroll 1
    for (int mtd = 0; mtd < 4; mtd++) {
        const bf16* wrow = WkL + (mtd * 16 + l15) * 96;
        v8bf wk3[3];
#pragma unroll
        for (int kt = 0; kt < 3; kt++)
            wk3[kt] = *(const v8bf*)(wrow + kt * 32 + quad * 8);
        float4 bk4 = *(const float4*)(bkL + mtd * 16 + quad * 4);
#pragma unroll
        for (int ntr = 0; ntr < 2; ntr++) {
            v4f acc = {0.f, 0.f, 0.f, 0.f};
#pragma unroll
            for (int kt = 0; kt < 3; kt++)
                acc = __builtin_amdgcn_mfma_f32_16x16x32_bf16(wk3[kt], xa[ntr][kt], acc, 0, 0, 0);
            int keyb = wave * 32 + ntr * 16 + l15;
            v4bf o;
            o[0] = (bf16)(acc[0] + bk4.x);
            o[1] = (bf16)(acc[1] + bk4.y);
            o[2] = (bf16)(acc[2] + bk4.z);
            o[3] = (bf16)(acc[3] + bk4.w);
            *(v4bf*)(Kb + keyb * 128 +
                     ((((mtd * 2 + (quad >> 1)) ^ (keyb & 7)) << 4) | ((quad & 1) << 3))) = o;
        }
    }
    __syncthreads();                         // BAR3: K tile + vsum complete

    // ---- Phase B: S^T = K @ Q^T, exp2, weighted accumulate with vsum ----
    float osum[2] = {0.f, 0.f};
    float lsum[2] = {0.f, 0.f};
#pragma unroll 2
    for (int t = 0; t < 16; t++) {
        v8bf kf[2][2];
#pragma unroll
        for (int mtk = 0; mtk < 2; mtk++)
#pragma unroll
            for (int kt = 0; kt < 2; kt++) {
                int key = t * 32 + mtk * 16 + l15;
                kf[mtk][kt] = *(const v8bf*)(Kb + key * 128 + (((kt * 4 + quad) ^ (key & 7)) << 4));
            }
        v4f vs[2];
#pragma unroll
        for (int mtk = 0; mtk < 2; mtk++)
            vs[mtk] = *(const v4f*)(vsum + t * 32 + mtk * 16 + quad * 4);
#pragma unroll
        for (int mtk = 0; mtk < 2; mtk++) {
#pragma unroll
            for (int nt = 0; nt < 2; nt++) {
                v4f acc = {0.f, 0.f, 0.f, 0.f};
                acc = __builtin_amdgcn_mfma_f32_16x16x32_bf16(kf[mtk][0], qf[nt][0], acc, 0, 0, 0);
                acc = __builtin_amdgcn_mfma_f32_16x16x32_bf16(kf[mtk][1], qf[nt][1], acc, 0, 0, 0);
                float p0 = __builtin_amdgcn_exp2f(acc[0]);
                float p1 = __builtin_amdgcn_exp2f(acc[1]);
                float p2 = __builtin_amdgcn_exp2f(acc[2]);
                float p3 = __builtin_amdgcn_exp2f(acc[3]);
                lsum[nt] += (p0 + p1) + (p2 + p3);
                osum[nt] += ((p0 * vs[mtk][0] + p1 * vs[mtk][1]) +
                             (p2 * vs[mtk][2] + p3 * vs[mtk][3]));
            }
        }
    }

    // ---- epilogue: reduce over key-quads, out = osum/lsum ----
#pragma unroll
    for (int nt = 0; nt < 2; nt++) {
        float lv = lsum[nt];
        lv += __shfl_xor(lv, 16);
        lv += __shfl_xor(lv, 32);
        float ov = osum[nt];
        ov += __shfl_xor(ov, 16);
        ov += __shfl_xor(ov, 32);
        if (quad == 0) out[rowbase + nt * 16 + l15] = ov / lv;
    }
}

extern "C" void kernel_launch(void* const* d_in, const int* in_sizes, int n_in,
                              void* d_out, int out_size, void* d_ws, size_t ws_size,
                              hipStream_t stream) {
    const float* power = (const float*)d_in[0];
    const int*   ele_i = (const int*)d_in[1];
    // d_in[2] = range_indices: unused by the reference (positional reshape)
    const int*   azi_i = (const int*)d_in[3];
    const float* ele_t = (const float*)d_in[4];
    const float* azi_t = (const float*)d_in[5];
    const float* Wq = (const float*)d_in[6];
    const float* bq = (const float*)d_in[7];
    const float* Wk = (const float*)d_in[8];
    const float* bk = (const float*)d_in[9];
    const float* Wv = (const float*)d_in[10];
    const float* bv = (const float*)d_in[11];
    float* out = (float*)d_out;

    // Kb 64K + vsum 2K + wvs 512B + WqL 12K + WkL 12K + bqL 256B + bkL 256B
    const int lds_bytes = 93184;
    (void)hipFuncSetAttribute(reinterpret_cast<const void*>(sda_kernel),
                              hipFuncAttributeMaxDynamicSharedMemorySize, lds_bytes);
    sda_kernel<<<256, 1024, lds_bytes, stream>>>(power, ele_i, azi_i, ele_t, azi_t,
                                                 Wq, bq, Wk, bk, Wv, bv, out);
}